// Round 1
// baseline (422.239 us; speedup 1.0000x reference)
//
#include <hip/hip_runtime.h>
#include <math.h>

// FourierKNOConv2d: x[8,32,256,256] f32, kernel[2,1,32,32,32,2] f32, r scalar.
// out[8,32,256,256] f32.
// Pipeline (all twiddles via incremental phasor rotation, fp32):
//   kP: Kp = (kr + i ki)^r                                  [2,32,32,32] c64
//   kA: Z1[b,c,y,w] = sum_x X[b,c,y,x] e^{-2pi i w x/256}, w<32
//   kB: Z2[b,c,t,w] = sum_y Z1[b,c,y,w] e^{-2pi i h(t) y/256}, t<64
//       h(t) = t<32 ? t : 192+t   (rows 0..31 and 224..255)
//   kC: G[b,co,t,w] = (1/8192) * sum_cf e^{+2pi i cf co/32} Kp[s,cf,m,w]
//                       * sum_ci e^{-2pi i cf ci/32} Z2[b,ci,t,w]
//       (1/8192 = forward-ortho 1/256 * channel-ortho 1/32)
//   kD: T[b,c,y,w] = sum_t G[b,c,t,w] e^{+2pi i h(t) y/256}
//   kE: out[b,c,y,x] = (1/256)*(Re T[y,0] + 2*sum_{w=1..31} Re(T[y,w] e^{+2pi i w x/256}))
// Workspace (needs >= 25 MB): z1r 8MB@0, z1i 8MB@8M, z2 4MB@16M, g 4MB@20M,
// kp 0.5MB@24M; T 16MB aliases z1 (dead after kB).

#define TWO_PI 6.28318530717958647692f

__global__ __launch_bounds__(256) void kP(const float* __restrict__ kin,
                                          const float* __restrict__ rp,
                                          float2* __restrict__ kp) {
  const int i = blockIdx.x * 256 + threadIdx.x;  // < 65536
  const float r = rp[0];
  const float kr = kin[2 * i], ki = kin[2 * i + 1];
  const float m2 = fmaf(kr, kr, ki * ki);
  float2 o = make_float2(0.f, 0.f);
  if (m2 > 0.f) {
    const float lm = 0.5f * logf(m2);
    const float ang = atan2f(ki, kr);
    const float mag = expf(r * lm);
    float s, c;
    sincosf(r * ang, &s, &c);
    o = make_float2(mag * c, mag * s);
  }
  kp[i] = o;
}

// A: per block: 8 rows of 256 pixels. thread = (row r=tid>>5, w=tid&31).
__global__ __launch_bounds__(256) void kA(const float* __restrict__ x,
                                          float* __restrict__ z1r,
                                          float* __restrict__ z1i) {
  __shared__ float xs[8 * 256];
  const long base = (long)blockIdx.x * (8 * 256);
  const float4* xg = (const float4*)(x + base);
  float4* xsv = (float4*)xs;
#pragma unroll
  for (int i = 0; i < 2; ++i) xsv[threadIdx.x + 256 * i] = xg[threadIdx.x + 256 * i];
  __syncthreads();
  const int w = threadIdx.x & 31;
  const int r = threadIdx.x >> 5;
  const float* row = xs + (r << 8);
  float rr, ri;
  sincosf(-TWO_PI * (float)w / 256.0f, &ri, &rr);  // rot = e^{-2pi i w/256}
  float cr = 1.f, ci = 0.f, ar = 0.f, ai = 0.f;
#pragma unroll 8
  for (int k = 0; k < 256; ++k) {
    const float v = row[k];
    ar = fmaf(v, cr, ar);
    ai = fmaf(v, ci, ai);
    const float t = fmaf(cr, rr, -ci * ri);
    ci = fmaf(cr, ri, ci * rr);
    cr = t;
  }
  const long rowg = (long)blockIdx.x * 8 + r;
  z1r[rowg * 32 + w] = ar;
  z1i[rowg * 32 + w] = ai;
}

// B: block per (b,c). LDS holds Z1 slice [256][32]. thread = (tb=tid>>5, w).
// Each thread accumulates 8 t-outputs (t = tb*8+k) over y with 8 phasors.
__global__ __launch_bounds__(256) void kB(const float* __restrict__ z1r,
                                          const float* __restrict__ z1i,
                                          float2* __restrict__ z2) {
  __shared__ float2 zs[256 * 32];  // 64 KB
  const int bc = blockIdx.x;
  const float* pr = z1r + (long)bc * 8192;
  const float* pi = z1i + (long)bc * 8192;
  for (int i = threadIdx.x; i < 8192; i += 256) zs[i] = make_float2(pr[i], pi[i]);
  __syncthreads();
  const int w = threadIdx.x & 31;
  const int tb = threadIdx.x >> 5;
  float ar[8], ai[8], cr[8], ci[8], rr[8], ri[8];
#pragma unroll
  for (int k = 0; k < 8; ++k) {
    const int t = tb * 8 + k;
    const int h = (t < 32) ? t : (192 + t);
    sincosf(-TWO_PI * (float)h / 256.0f, &ri[k], &rr[k]);
    ar[k] = 0.f; ai[k] = 0.f; cr[k] = 1.f; ci[k] = 0.f;
  }
  for (int y = 0; y < 256; ++y) {
    const float2 z = zs[y * 32 + w];
#pragma unroll
    for (int k = 0; k < 8; ++k) {
      ar[k] = fmaf(z.x, cr[k], fmaf(-z.y, ci[k], ar[k]));
      ai[k] = fmaf(z.x, ci[k], fmaf(z.y, cr[k], ai[k]));
      const float t2 = fmaf(cr[k], rr[k], -ci[k] * ri[k]);
      ci[k] = fmaf(cr[k], ri[k], ci[k] * rr[k]);
      cr[k] = t2;
    }
  }
#pragma unroll
  for (int k = 0; k < 8; ++k) {
    const int t = tb * 8 + k;
    z2[(long)bc * 2048 + t * 32 + w] = make_float2(ar[k], ai[k]);
  }
}

// C: thread per mode (b,t,w); DFT32 over channels, * Kp, iDFT32.
__global__ __launch_bounds__(64) void kC(const float2* __restrict__ z2,
                                         const float2* __restrict__ kp,
                                         float2* __restrict__ g) {
  __shared__ float2 tw[32];  // e^{-2pi i k/32}
  if (threadIdx.x < 32) {
    float s, c;
    sincosf(-TWO_PI * (float)threadIdx.x / 32.0f, &s, &c);
    tw[threadIdx.x] = make_float2(c, s);
  }
  __syncthreads();
  const int gid = blockIdx.x * 64 + threadIdx.x;  // < 16384
  const int w = gid & 31;
  const int t = (gid >> 5) & 63;
  const int b = gid >> 11;
  const int s_ = t >> 5;
  const int m = t & 31;
  float2 v[32];
#pragma unroll
  for (int c = 0; c < 32; ++c)
    v[c] = z2[(((long)b * 32 + c) * 64 + t) * 32 + w];
  float gr[32], gi[32];
#pragma unroll
  for (int co = 0; co < 32; ++co) { gr[co] = 0.f; gi[co] = 0.f; }
  for (int cf = 0; cf < 32; ++cf) {
    float fr = 0.f, fi = 0.f;
    int idx = 0;
#pragma unroll
    for (int c = 0; c < 32; ++c) {
      const float2 tt = tw[idx];
      idx = (idx + cf) & 31;
      fr = fmaf(v[c].x, tt.x, fmaf(-v[c].y, tt.y, fr));
      fi = fmaf(v[c].x, tt.y, fmaf(v[c].y, tt.x, fi));
    }
    const float2 k = kp[((s_ * 32 + cf) * 32 + m) * 32 + w];
    const float fmr = fr * k.x - fi * k.y;
    const float fmi = fr * k.y + fi * k.x;
    int idx2 = 0;
#pragma unroll
    for (int co = 0; co < 32; ++co) {
      const float2 tt = tw[idx2];  // e^{-i th}; we need e^{+i th} = conj
      idx2 = (idx2 + cf) & 31;
      gr[co] = fmaf(fmr, tt.x, fmaf(fmi, tt.y, gr[co]));
      gi[co] = fmaf(fmi, tt.x, fmaf(-fmr, tt.y, gi[co]));
    }
  }
  const float SC = 1.0f / 8192.0f;
#pragma unroll
  for (int co = 0; co < 32; ++co)
    g[(((long)b * 32 + co) * 64 + t) * 32 + w] = make_float2(gr[co] * SC, gi[co] * SC);
}

// D: block per (b,c). LDS: G slice [64][32] + 256-entry phase table.
// thread = (yg=tid>>5, w); 32 consecutive y per thread, loop t outer.
__global__ __launch_bounds__(256) void kD(const float2* __restrict__ g,
                                          float2* __restrict__ tbuf) {
  __shared__ float2 gs[64 * 32];  // 16 KB
  __shared__ float2 tab[256];     // e^{+2pi i k/256}
  const int bc = blockIdx.x;
  const float2* src = g + (long)bc * 2048;
  for (int i = threadIdx.x; i < 2048; i += 256) gs[i] = src[i];
  {
    float s, c;
    sincosf(TWO_PI * (float)threadIdx.x / 256.0f, &s, &c);
    tab[threadIdx.x] = make_float2(c, s);
  }
  __syncthreads();
  const int w = threadIdx.x & 31;
  const int yg = threadIdx.x >> 5;
  const int y0 = yg * 32;
  float ar[32], ai[32];
#pragma unroll
  for (int j = 0; j < 32; ++j) { ar[j] = 0.f; ai[j] = 0.f; }
  for (int t = 0; t < 64; ++t) {
    const int h = (t < 32) ? t : (192 + t);
    const float2 gv = gs[t * 32 + w];
    const float2 p0 = tab[(h * y0) & 255];
    const float2 rt = tab[h];
    float cr = p0.x, ci = p0.y;
#pragma unroll
    for (int j = 0; j < 32; ++j) {
      ar[j] = fmaf(gv.x, cr, fmaf(-gv.y, ci, ar[j]));
      ai[j] = fmaf(gv.x, ci, fmaf(gv.y, cr, ai[j]));
      const float t2 = fmaf(cr, rt.x, -ci * rt.y);
      ci = fmaf(cr, rt.y, ci * rt.x);
      cr = t2;
    }
  }
#pragma unroll
  for (int j = 0; j < 32; ++j)
    tbuf[(long)bc * 8192 + (y0 + j) * 32 + w] = make_float2(ar[j], ai[j]);
}

// E: block per row (b,c,y); thread per x.
__global__ __launch_bounds__(256) void kE(const float2* __restrict__ tbuf,
                                          float* __restrict__ out) {
  __shared__ float2 ts[32];
  const long row = blockIdx.x;  // 65536 rows
  if (threadIdx.x < 32) ts[threadIdx.x] = tbuf[row * 32 + threadIdx.x];
  __syncthreads();
  const int xx = threadIdx.x;
  float s1, c1;
  sincosf(TWO_PI * (float)xx / 256.0f, &s1, &c1);
  float cr = c1, ci = s1;
  float acc = ts[0].x;  // irfft ignores imag of DC bin
#pragma unroll 8
  for (int w = 1; w < 32; ++w) {
    const float2 tv = ts[w];
    acc = fmaf(2.f * tv.x, cr, fmaf(-2.f * tv.y, ci, acc));
    const float t2 = fmaf(cr, c1, -ci * s1);
    ci = fmaf(cr, s1, ci * c1);
    cr = t2;
  }
  out[row * 256 + xx] = acc * (1.0f / 256.0f);
}

extern "C" void kernel_launch(void* const* d_in, const int* in_sizes, int n_in,
                              void* d_out, int out_size, void* d_ws, size_t ws_size,
                              hipStream_t stream) {
  const float* x = (const float*)d_in[0];
  const float* kin = (const float*)d_in[1];
  const float* rp = (const float*)d_in[2];
  float* out = (float*)d_out;
  char* ws = (char*)d_ws;

  float* z1r = (float*)(ws);                        // 8 MB
  float* z1i = (float*)(ws + (8ull << 20));         // 8 MB
  float2* tbuf = (float2*)(ws);                     // 16 MB (aliases z1, used after z1 dead)
  float2* z2 = (float2*)(ws + (16ull << 20));       // 4 MB
  float2* g = (float2*)(ws + (20ull << 20));        // 4 MB
  float2* kp = (float2*)(ws + (24ull << 20));       // 512 KB

  kP<<<256, 256, 0, stream>>>(kin, rp, kp);
  kA<<<8192, 256, 0, stream>>>(x, z1r, z1i);
  kB<<<256, 256, 0, stream>>>(z1r, z1i, z2);
  kC<<<256, 64, 0, stream>>>(z2, kp, g);
  kD<<<256, 256, 0, stream>>>(g, tbuf);
  kE<<<65536, 256, 0, stream>>>(tbuf, out);
}

// Round 2
// 249.088 us; speedup vs baseline: 1.6951x; 1.6951x over previous
//
#include <hip/hip_runtime.h>
#include <math.h>

// FourierKNOConv2d: x[8,32,256,256] f32, kernel[2,1,32,32,32,2] f32, r scalar.
// out[8,32,256,256] f32.
//   kP: Kp = (kr + i ki)^r                                  [2,32,32,32] c64
//   kA: Z1[row,w] = sum_x X[row,x] e^{-2pi i w x/256}, w<32  (table twiddles)
//   kB: Z2[bc,t,w] = sum_y Z1[bc,y,w] e^{-2pi i h(t) y/256}, h(t)=t<32?t:192+t
//   kC: G = idft32_ch( dft32_ch(Z2) * Kp ) / 8192
//   kD: T[bc,y,w] = sum_t G[bc,t,w] e^{+2pi i h(t) y/256}
//   kE: out[row,x] = (1/256)(Re T[row,0] + 2 sum_{w>=1} Re(T[row,w] e^{+2pi i w x/256}))
// ws: z1/tbuf 16MB@0 (aliased; z1 dead after kB), z2 4MB@16M, g 4MB@20M, kp 512KB@24M.

#define TWO_PI 6.28318530717958647692f

__global__ __launch_bounds__(256) void kP(const float* __restrict__ kin,
                                          const float* __restrict__ rp,
                                          float2* __restrict__ kp) {
  const int i = blockIdx.x * 256 + threadIdx.x;  // < 65536
  const float r = rp[0];
  const float kr = kin[2 * i], ki = kin[2 * i + 1];
  const float m2 = fmaf(kr, kr, ki * ki);
  float2 o = make_float2(0.f, 0.f);
  if (m2 > 0.f) {
    const float lm = 0.5f * logf(m2);
    const float ang = atan2f(ki, kr);
    const float mag = expf(r * lm);
    float s, c;
    sincosf(r * ang, &s, &c);
    o = make_float2(mag * c, mag * s);
  }
  kp[i] = o;
}

// kA: grid 2048 blocks; block covers 32 rows x 32 w. Thread = (w=tid&31, rg=tid>>5),
// accumulates 4 rows. x staged transposed+swizzled: phys = x*32 + ((4*rg) ^ ((x&7)<<2)).
__global__ __launch_bounds__(256) void kA(const float* __restrict__ x,
                                          float2* __restrict__ z1) {
  __shared__ float4 xs4[2048];   // 32 KB, holds transposed [x][r] swizzled
  __shared__ float2 tab[256];    // e^{-2pi i k/256}
  float* xs = (float*)xs4;
  const int tid = threadIdx.x;
  const long row0 = (long)blockIdx.x * 32;
  {
    float s, c;
    sincosf(-TWO_PI * (float)tid / 256.0f, &s, &c);
    tab[tid] = make_float2(c, s);
  }
  const float* xg = x + row0 * 256;
#pragma unroll
  for (int rg = 0; rg < 8; ++rg) {
    float4 v;
    v.x = xg[(rg * 4 + 0) * 256 + tid];
    v.y = xg[(rg * 4 + 1) * 256 + tid];
    v.z = xg[(rg * 4 + 2) * 256 + tid];
    v.w = xg[(rg * 4 + 3) * 256 + tid];
    *(float4*)(xs + tid * 32 + ((rg * 4) ^ ((tid & 7) << 2))) = v;
  }
  __syncthreads();
  const int w = tid & 31;
  const int rg4 = (tid >> 5) << 2;
  float ar0 = 0, ar1 = 0, ar2 = 0, ar3 = 0;
  float ai0 = 0, ai1 = 0, ai2 = 0, ai3 = 0;
  int idx = 0;
#pragma unroll 8
  for (int xx = 0; xx < 256; ++xx) {
    const float4 v = *(const float4*)(xs + xx * 32 + (rg4 ^ ((xx & 7) << 2)));
    const float2 t = tab[idx];
    idx = (idx + w) & 255;
    ar0 = fmaf(v.x, t.x, ar0); ai0 = fmaf(v.x, t.y, ai0);
    ar1 = fmaf(v.y, t.x, ar1); ai1 = fmaf(v.y, t.y, ai1);
    ar2 = fmaf(v.z, t.x, ar2); ai2 = fmaf(v.z, t.y, ai2);
    ar3 = fmaf(v.w, t.x, ar3); ai3 = fmaf(v.w, t.y, ai3);
  }
  float2* o = z1 + (row0 + rg4) * 32 + w;
  o[0]  = make_float2(ar0, ai0);
  o[32] = make_float2(ar1, ai1);
  o[64] = make_float2(ar2, ai2);
  o[96] = make_float2(ar3, ai3);
}

// kB: grid 1024 = (bc, wg of 8 w). Thread = (t=tid>>2, wp=tid&3): 1 t x 2 w.
// Per-thread phasor rotation (step depends only on t).
__global__ __launch_bounds__(256) void kB(const float2* __restrict__ z1,
                                          float2* __restrict__ z2) {
  __shared__ float2 zs[2048];  // [y][wi<8], 16 KB
  const int bc = blockIdx.x >> 2;
  const int wg = blockIdx.x & 3;
  const float2* src = z1 + (long)bc * 8192 + wg * 8;
  for (int i = threadIdx.x; i < 2048; i += 256) {
    const int y = i >> 3, wi = i & 7;
    zs[i] = src[y * 32 + wi];
  }
  __syncthreads();
  const int t = threadIdx.x >> 2;
  const int wp = threadIdx.x & 3;
  const int h = (t < 32) ? t : (192 + t);
  float sr, cr;
  sincosf(-TWO_PI * (float)h / 256.0f, &sr, &cr);
  float pc = 1.f, ps = 0.f;
  float a0r = 0, a0i = 0, a1r = 0, a1i = 0;
  for (int y = 0; y < 256; ++y) {
    const float4 z = *(const float4*)(zs + y * 8 + 2 * wp);
    a0r = fmaf(z.x, pc, fmaf(-z.y, ps, a0r));
    a0i = fmaf(z.x, ps, fmaf( z.y, pc, a0i));
    a1r = fmaf(z.z, pc, fmaf(-z.w, ps, a1r));
    a1i = fmaf(z.z, ps, fmaf( z.w, pc, a1i));
    const float tn = fmaf(pc, cr, -ps * sr);
    ps = fmaf(pc, sr, ps * cr);
    pc = tn;
  }
  *(float4*)(z2 + (long)bc * 2048 + t * 32 + wg * 8 + 2 * wp) =
      make_float4(a0r, a0i, a1r, a1i);
}

// kC: grid 1024; block = 16 modes (same b,t; w = w0..w0+15). Two LDS phases.
__global__ __launch_bounds__(256) void kC(const float2* __restrict__ z2,
                                          const float2* __restrict__ kp,
                                          float2* __restrict__ g) {
  __shared__ float2 z2s[16 * 33];  // [m][ci], padded
  __shared__ float2 fk[16 * 33];   // [m][cf], padded
  __shared__ float2 tw[32];        // e^{-2pi i k/32}
  const int tid = threadIdx.x;
  if (tid < 32) {
    float s, c;
    sincosf(-TWO_PI * (float)tid / 32.0f, &s, &c);
    tw[tid] = make_float2(c, s);
  }
  const int m0 = blockIdx.x * 16;
  const int b = m0 >> 11;
  const int twi = m0 & 2047;
  const int t = twi >> 5;
  const int w0 = twi & 31;  // 0 or 16
  const int s_ = t >> 5, tm = t & 31;
  for (int i = tid; i < 512; i += 256) {
    const int ci = i >> 4, wj = i & 15;
    z2s[wj * 33 + ci] = z2[((long)(b * 32 + ci)) * 2048 + t * 32 + w0 + wj];
  }
  __syncthreads();
  const int m = tid & 15;
  const int p = tid >> 4;
  const int cf0 = 2 * p, cf1 = 2 * p + 1;
  {
    float f0r = 0, f0i = 0, f1r = 0, f1i = 0;
    int i0 = 0, i1 = 0;
#pragma unroll 8
    for (int ci = 0; ci < 32; ++ci) {
      const float2 z = z2s[m * 33 + ci];
      const float2 t0 = tw[i0]; i0 = (i0 + cf0) & 31;
      const float2 t1 = tw[i1]; i1 = (i1 + cf1) & 31;
      f0r = fmaf(z.x, t0.x, fmaf(-z.y, t0.y, f0r));
      f0i = fmaf(z.x, t0.y, fmaf( z.y, t0.x, f0i));
      f1r = fmaf(z.x, t1.x, fmaf(-z.y, t1.y, f1r));
      f1i = fmaf(z.x, t1.y, fmaf( z.y, t1.x, f1i));
    }
    const float2 k0 = kp[((s_ * 32 + cf0) * 32 + tm) * 32 + w0 + m];
    const float2 k1 = kp[((s_ * 32 + cf1) * 32 + tm) * 32 + w0 + m];
    fk[m * 33 + cf0] = make_float2(f0r * k0.x - f0i * k0.y, f0r * k0.y + f0i * k0.x);
    fk[m * 33 + cf1] = make_float2(f1r * k1.x - f1i * k1.y, f1r * k1.y + f1i * k1.x);
  }
  __syncthreads();
  {
    float g0r = 0, g0i = 0, g1r = 0, g1i = 0;
    int i0 = 0, i1 = 0;
    const int co0 = 2 * p, co1 = 2 * p + 1;
#pragma unroll 8
    for (int cf = 0; cf < 32; ++cf) {
      const float2 f = fk[m * 33 + cf];
      const float2 t0 = tw[i0]; i0 = (i0 + co0) & 31;
      const float2 t1 = tw[i1]; i1 = (i1 + co1) & 31;
      // multiply by conj(tw) = e^{+i th}
      g0r = fmaf(f.x, t0.x, fmaf( f.y, t0.y, g0r));
      g0i = fmaf(f.y, t0.x, fmaf(-f.x, t0.y, g0i));
      g1r = fmaf(f.x, t1.x, fmaf( f.y, t1.y, g1r));
      g1i = fmaf(f.y, t1.x, fmaf(-f.x, t1.y, g1i));
    }
    const float SC = 1.0f / 8192.0f;
    g[((long)(b * 32 + co0)) * 2048 + t * 32 + w0 + m] = make_float2(g0r * SC, g0i * SC);
    g[((long)(b * 32 + co1)) * 2048 + t * 32 + w0 + m] = make_float2(g1r * SC, g1i * SC);
  }
}

// kD: grid 4096 = (bc, yg of 64 y, wg of 8 w). Thread = (y=tid>>2, wp=tid&3).
// Phasor step e^{+2pi i y/256} is loop-invariant; two t-segments.
__global__ __launch_bounds__(256) void kD(const float2* __restrict__ g,
                                          float2* __restrict__ tb) {
  __shared__ float2 gs[512];  // [t][wi<8], 4 KB
  const int bc = blockIdx.x >> 4;
  const int yg = (blockIdx.x >> 2) & 3;
  const int wg = blockIdx.x & 3;
  const float2* src = g + (long)bc * 2048 + wg * 8;
  for (int i = threadIdx.x; i < 512; i += 256) {
    const int t = i >> 3, wi = i & 7;
    gs[i] = src[t * 32 + wi];
  }
  __syncthreads();
  const int y = yg * 64 + (threadIdx.x >> 2);
  const int wp = threadIdx.x & 3;
  float sr, cr;
  sincosf(TWO_PI * (float)y / 256.0f, &sr, &cr);
  float a0r = 0, a0i = 0, a1r = 0, a1i = 0;
  float pc = 1.f, ps = 0.f;
  for (int t = 0; t < 32; ++t) {
    const float4 gv = *(const float4*)(gs + t * 8 + 2 * wp);
    a0r = fmaf(gv.x, pc, fmaf(-gv.y, ps, a0r));
    a0i = fmaf(gv.x, ps, fmaf( gv.y, pc, a0i));
    a1r = fmaf(gv.z, pc, fmaf(-gv.w, ps, a1r));
    a1i = fmaf(gv.z, ps, fmaf( gv.w, pc, a1i));
    const float tn = fmaf(pc, cr, -ps * sr);
    ps = fmaf(pc, sr, ps * cr);
    pc = tn;
  }
  {
    float s2, c2;
    sincosf(TWO_PI * (float)((224 * y) & 255) / 256.0f, &s2, &c2);
    pc = c2; ps = s2;
  }
  for (int t = 32; t < 64; ++t) {
    const float4 gv = *(const float4*)(gs + t * 8 + 2 * wp);
    a0r = fmaf(gv.x, pc, fmaf(-gv.y, ps, a0r));
    a0i = fmaf(gv.x, ps, fmaf( gv.y, pc, a0i));
    a1r = fmaf(gv.z, pc, fmaf(-gv.w, ps, a1r));
    a1i = fmaf(gv.z, ps, fmaf( gv.w, pc, a1i));
    const float tn = fmaf(pc, cr, -ps * sr);
    ps = fmaf(pc, sr, ps * cr);
    pc = tn;
  }
  *(float4*)(tb + (long)bc * 8192 + y * 32 + wg * 8 + 2 * wp) =
      make_float4(a0r, a0i, a1r, a1i);
}

// kE: grid 4096; block = 16 rows x 256 x. Thread = x, 16-row accumulator tile.
// T staged transposed [w][r] (stride 18 float2) with 2/256 (1/256 for w=0) folded in.
__global__ __launch_bounds__(256) void kE(const float2* __restrict__ tb,
                                          float* __restrict__ out) {
  __shared__ float2 tst[32 * 18];  // ~4.6 KB
  const long row0 = (long)blockIdx.x * 16;
  const int tid = threadIdx.x;
  for (int i = tid; i < 512; i += 256) {
    const int w = i & 31, r = i >> 5;
    float2 v = tb[(row0 + r) * 32 + w];
    const float sc = (w == 0) ? (1.0f / 256.0f) : (2.0f / 256.0f);
    tst[w * 18 + r] = make_float2(v.x * sc, v.y * sc);
  }
  __syncthreads();
  float s1, c1;
  sincosf(TWO_PI * (float)tid / 256.0f, &s1, &c1);
  float pc = c1, ps = s1;
  float acc[16];
#pragma unroll
  for (int r = 0; r < 16; ++r) acc[r] = tst[r].x;  // w=0: Re only, scaled
  for (int w = 1; w < 32; ++w) {
    const float2* tv = tst + w * 18;
#pragma unroll
    for (int r = 0; r < 16; ++r) {
      const float2 T = tv[r];
      acc[r] = fmaf(T.x, pc, fmaf(-T.y, ps, acc[r]));
    }
    const float tn = fmaf(pc, c1, -ps * s1);
    ps = fmaf(pc, s1, ps * c1);
    pc = tn;
  }
#pragma unroll
  for (int r = 0; r < 16; ++r) out[(row0 + r) * 256 + tid] = acc[r];
}

extern "C" void kernel_launch(void* const* d_in, const int* in_sizes, int n_in,
                              void* d_out, int out_size, void* d_ws, size_t ws_size,
                              hipStream_t stream) {
  const float* x = (const float*)d_in[0];
  const float* kin = (const float*)d_in[1];
  const float* rp = (const float*)d_in[2];
  float* out = (float*)d_out;
  char* ws = (char*)d_ws;

  float2* z1 = (float2*)(ws);                   // 16 MB [65536 rows][32 w]
  float2* tb = (float2*)(ws);                   // aliases z1 (dead after kB)
  float2* z2 = (float2*)(ws + (16ull << 20));   // 4 MB
  float2* g  = (float2*)(ws + (20ull << 20));   // 4 MB
  float2* kp = (float2*)(ws + (24ull << 20));   // 512 KB

  kP<<<256, 256, 0, stream>>>(kin, rp, kp);
  kA<<<2048, 256, 0, stream>>>(x, z1);
  kB<<<1024, 256, 0, stream>>>(z1, z2);
  kC<<<1024, 256, 0, stream>>>(z2, kp, g);
  kD<<<4096, 256, 0, stream>>>(g, tb);
  kE<<<4096, 256, 0, stream>>>(tb, out);
}

// Round 3
// 211.664 us; speedup vs baseline: 1.9949x; 1.1768x over previous
//
#include <hip/hip_runtime.h>
#include <math.h>

// FourierKNOConv2d: x[8,32,256,256] f32, kernel[2,1,32,32,32,2] f32, r scalar.
// out[8,32,256,256] f32.
//   kP: Kp = (kr + i ki)^r                                  [2,32,32,32] c64
//   kA: Z1[row,w] = sum_x X[row,x] e^{-2pi i w x/256}, w<32  (x<->256-x symmetry)
//   kB: Z2[bc,t,w] = sum_y Z1[bc,y,w] e^{-2pi i h(t) y/256}, h(t)=t<32?t:192+t
//       (split y into two halves -> z2a + z2b, summed in kC)
//   kC: G = idft32_ch( dft32_ch(z2a+z2b) * Kp ) / 8192
//   kD: T[bc,y,w] = sum_t G[bc,t,w] e^{+2pi i h(t) y/256}
//   kE: out[row,x] = C(x)-S(x), out[row,256-x] = C(x)+S(x)  (x-symmetry; col 128 special)
// ws map (24.5 MB, stream-ordered reuse):
//   z1  @0..16M    (kA w, kB r)
//   z2a @16..20M, z2b @20..24M (kB w, kC r)
//   kp  @24..24.5M (kP w, kC r)
//   g   @0..4M     (kC w, kD r; over dead z1)
//   tb  @4..20M    (kD w, kE r; over dead z1/z2a)

#define TWO_PI 6.28318530717958647692f

__global__ __launch_bounds__(256) void kP(const float* __restrict__ kin,
                                          const float* __restrict__ rp,
                                          float2* __restrict__ kp) {
  const int i = blockIdx.x * 256 + threadIdx.x;  // < 65536
  const float r = rp[0];
  const float kr = kin[2 * i], ki = kin[2 * i + 1];
  const float m2 = fmaf(kr, kr, ki * ki);
  float2 o = make_float2(0.f, 0.f);
  if (m2 > 0.f) {
    const float lm = 0.5f * logf(m2);
    const float ang = atan2f(ki, kr);
    const float mag = expf(r * lm);
    float s, c;
    sincosf(r * ang, &s, &c);
    o = make_float2(mag * c, mag * s);
  }
  kp[i] = o;
}

// kA: 2048 blocks; block = 32 rows. LDS [x][r] stride 36 (16B-aligned float4 reads).
// Pass1 stage transposed; pass2 replace x/(256-x) with u=a+b (slot x), v=a-b (slot 256-x).
// Thread = (w=tid&31, rq=tid>>5): 4 rows. 127-iter phasor loop + edge terms x=0,128.
__global__ __launch_bounds__(256) void kA(const float* __restrict__ x,
                                          float2* __restrict__ z1) {
  __shared__ float xs[256 * 36];  // 36 KB
  const int tid = threadIdx.x;
  const long row0 = (long)blockIdx.x * 32;
  const float* xg = x + row0 * 256;
#pragma unroll 4
  for (int r = 0; r < 32; ++r) xs[tid * 36 + r] = xg[r * 256 + tid];
  __syncthreads();
  for (int i = tid; i < 127 * 32; i += 256) {
    const int xi = 1 + (i >> 5), r = i & 31;
    const float a = xs[xi * 36 + r], b = xs[(256 - xi) * 36 + r];
    xs[xi * 36 + r] = a + b;          // u
    xs[(256 - xi) * 36 + r] = a - b;  // v
  }
  __syncthreads();
  const int w = tid & 31;
  const int r0 = (tid >> 5) << 2;
  // edge terms: Re += X(0) + (-1)^w X(128)
  const float sgn = (w & 1) ? -1.f : 1.f;
  const float4 x0 = *(const float4*)(xs + r0);
  const float4 x128 = *(const float4*)(xs + 128 * 36 + r0);
  float Cr0 = fmaf(sgn, x128.x, x0.x), Cr1 = fmaf(sgn, x128.y, x0.y);
  float Cr2 = fmaf(sgn, x128.z, x0.z), Cr3 = fmaf(sgn, x128.w, x0.w);
  float Ci0 = 0, Ci1 = 0, Ci2 = 0, Ci3 = 0;
  float s1, c1;
  sincosf(TWO_PI * (float)w / 256.0f, &s1, &c1);
  float pc = c1, ps = s1;  // phasor at x=1 (positive angle; sign applied on Im)
  const float* pu = xs + 36 + r0;
  const float* pv = xs + 255 * 36 + r0;
  for (int xx = 1; xx < 128; ++xx) {
    const float4 u = *(const float4*)pu;
    const float4 v = *(const float4*)pv;
    pu += 36; pv -= 36;
    Cr0 = fmaf(u.x, pc, Cr0); Ci0 = fmaf(-v.x, ps, Ci0);
    Cr1 = fmaf(u.y, pc, Cr1); Ci1 = fmaf(-v.y, ps, Ci1);
    Cr2 = fmaf(u.z, pc, Cr2); Ci2 = fmaf(-v.z, ps, Ci2);
    Cr3 = fmaf(u.w, pc, Cr3); Ci3 = fmaf(-v.w, ps, Ci3);
    const float tn = fmaf(pc, c1, -ps * s1);
    ps = fmaf(pc, s1, ps * c1);
    pc = tn;
  }
  float2* o = z1 + (row0 + r0) * 32 + w;
  o[0]  = make_float2(Cr0, Ci0);
  o[32] = make_float2(Cr1, Ci1);
  o[64] = make_float2(Cr2, Ci2);
  o[96] = make_float2(Cr3, Ci3);
}

// kB: 512 blocks = (bc, yh). Thread = (t=tid>>2, wq=tid&3): 8 w per thread.
// Partial over 128 y -> z2p[yh]. Phasor start (-1)^(h*yh), step e^{-2pi i h/256}.
__global__ __launch_bounds__(256) void kB(const float2* __restrict__ z1,
                                          float2* __restrict__ z2p) {
  __shared__ float2 zs[128 * 32];  // 32 KB, [y][w]
  const int bc = blockIdx.x >> 1, yh = blockIdx.x & 1;
  const float2* src = z1 + (long)bc * 8192 + yh * 4096;
  for (int i = threadIdx.x; i < 4096; i += 256) zs[i] = src[i];
  __syncthreads();
  const int t = threadIdx.x >> 2, wq = threadIdx.x & 3;
  const int h = (t < 32) ? t : (192 + t);
  float sr, cr;
  sincosf(-TWO_PI * (float)h / 256.0f, &sr, &cr);
  float pc = (yh && (t & 1)) ? -1.f : 1.f, ps = 0.f;
  float ar[8], ai[8];
#pragma unroll
  for (int k = 0; k < 8; ++k) { ar[k] = 0.f; ai[k] = 0.f; }
  const float* zb = (const float*)zs + wq * 16;
  for (int y = 0; y < 128; ++y) {
    const float4* zf = (const float4*)(zb + y * 64);
#pragma unroll
    for (int k = 0; k < 4; ++k) {
      const float4 q = zf[k];
      ar[2 * k]     = fmaf(q.x, pc, fmaf(-q.y, ps, ar[2 * k]));
      ai[2 * k]     = fmaf(q.x, ps, fmaf( q.y, pc, ai[2 * k]));
      ar[2 * k + 1] = fmaf(q.z, pc, fmaf(-q.w, ps, ar[2 * k + 1]));
      ai[2 * k + 1] = fmaf(q.z, ps, fmaf( q.w, pc, ai[2 * k + 1]));
    }
    const float tn = fmaf(pc, cr, -ps * sr);
    ps = fmaf(pc, sr, ps * cr);
    pc = tn;
  }
  float4* dst = (float4*)(z2p + (long)yh * 524288 + (long)bc * 2048 + t * 32 + wq * 8);
#pragma unroll
  for (int k = 0; k < 4; ++k)
    dst[k] = make_float4(ar[2 * k], ai[2 * k], ar[2 * k + 1], ai[2 * k + 1]);
}

// kC: 1024 blocks; block = 16 modes (same b,t; 16 w). Sums z2a+z2b at load.
__global__ __launch_bounds__(256) void kC(const float2* __restrict__ z2a,
                                          const float2* __restrict__ z2b,
                                          const float2* __restrict__ kp,
                                          float2* __restrict__ g) {
  __shared__ float2 z2s[16 * 33];
  __shared__ float2 fk[16 * 33];
  __shared__ float2 tw[32];
  const int tid = threadIdx.x;
  if (tid < 32) {
    float s, c;
    sincosf(-TWO_PI * (float)tid / 32.0f, &s, &c);
    tw[tid] = make_float2(c, s);
  }
  const int m0 = blockIdx.x * 16;
  const int b = m0 >> 11;
  const int twi = m0 & 2047;
  const int t = twi >> 5;
  const int w0 = twi & 31;
  const int s_ = t >> 5, tm = t & 31;
  for (int i = tid; i < 512; i += 256) {
    const int ci = i >> 4, wj = i & 15;
    const long idx = ((long)(b * 32 + ci)) * 2048 + t * 32 + w0 + wj;
    const float2 va = z2a[idx], vb = z2b[idx];
    z2s[wj * 33 + ci] = make_float2(va.x + vb.x, va.y + vb.y);
  }
  __syncthreads();
  const int m = tid & 15;
  const int p = tid >> 4;
  const int cf0 = 2 * p, cf1 = 2 * p + 1;
  {
    float f0r = 0, f0i = 0, f1r = 0, f1i = 0;
    int i0 = 0, i1 = 0;
#pragma unroll 8
    for (int ci = 0; ci < 32; ++ci) {
      const float2 z = z2s[m * 33 + ci];
      const float2 t0 = tw[i0]; i0 = (i0 + cf0) & 31;
      const float2 t1 = tw[i1]; i1 = (i1 + cf1) & 31;
      f0r = fmaf(z.x, t0.x, fmaf(-z.y, t0.y, f0r));
      f0i = fmaf(z.x, t0.y, fmaf( z.y, t0.x, f0i));
      f1r = fmaf(z.x, t1.x, fmaf(-z.y, t1.y, f1r));
      f1i = fmaf(z.x, t1.y, fmaf( z.y, t1.x, f1i));
    }
    const float2 k0 = kp[((s_ * 32 + cf0) * 32 + tm) * 32 + w0 + m];
    const float2 k1 = kp[((s_ * 32 + cf1) * 32 + tm) * 32 + w0 + m];
    fk[m * 33 + cf0] = make_float2(f0r * k0.x - f0i * k0.y, f0r * k0.y + f0i * k0.x);
    fk[m * 33 + cf1] = make_float2(f1r * k1.x - f1i * k1.y, f1r * k1.y + f1i * k1.x);
  }
  __syncthreads();
  {
    float g0r = 0, g0i = 0, g1r = 0, g1i = 0;
    int i0 = 0, i1 = 0;
    const int co0 = 2 * p, co1 = 2 * p + 1;
#pragma unroll 8
    for (int cf = 0; cf < 32; ++cf) {
      const float2 f = fk[m * 33 + cf];
      const float2 t0 = tw[i0]; i0 = (i0 + co0) & 31;
      const float2 t1 = tw[i1]; i1 = (i1 + co1) & 31;
      g0r = fmaf(f.x, t0.x, fmaf( f.y, t0.y, g0r));
      g0i = fmaf(f.y, t0.x, fmaf(-f.x, t0.y, g0i));
      g1r = fmaf(f.x, t1.x, fmaf( f.y, t1.y, g1r));
      g1i = fmaf(f.y, t1.x, fmaf(-f.x, t1.y, g1i));
    }
    const float SC = 1.0f / 8192.0f;
    g[((long)(b * 32 + co0)) * 2048 + t * 32 + w0 + m] = make_float2(g0r * SC, g0i * SC);
    g[((long)(b * 32 + co1)) * 2048 + t * 32 + w0 + m] = make_float2(g1r * SC, g1i * SC);
  }
}

// kD: 512 blocks = (bc, yh). Thread = (yl=tid>>1, wh=tid&1): 16 w per thread.
__global__ __launch_bounds__(256) void kD(const float2* __restrict__ g,
                                          float2* __restrict__ tb) {
  __shared__ float2 gs[64 * 32];  // 16 KB
  const int bc = blockIdx.x >> 1, yh = blockIdx.x & 1;
  const float2* src = g + (long)bc * 2048;
  for (int i = threadIdx.x; i < 2048; i += 256) gs[i] = src[i];
  __syncthreads();
  const int yl = threadIdx.x >> 1, wh = threadIdx.x & 1;
  const int y = yh * 128 + yl;
  float s1, c1;
  sincosf(TWO_PI * (float)y / 256.0f, &s1, &c1);  // step e^{+2pi i y/256}
  float Tr[16], Ti[16];
#pragma unroll
  for (int k = 0; k < 16; ++k) { Tr[k] = 0.f; Ti[k] = 0.f; }
  float pc = 1.f, ps = 0.f;
  const float* gb = (const float*)gs + wh * 32;
  for (int t = 0; t < 64; ++t) {
    if (t == 32) {
      float s2, c2;
      sincosf(TWO_PI * (float)((224 * y) & 255) / 256.0f, &s2, &c2);
      pc = c2; ps = s2;
    }
    const float4* gf = (const float4*)(gb + t * 64);
#pragma unroll
    for (int k = 0; k < 8; ++k) {
      const float4 q = gf[k];
      Tr[2 * k]     = fmaf(q.x, pc, fmaf(-q.y, ps, Tr[2 * k]));
      Ti[2 * k]     = fmaf(q.x, ps, fmaf( q.y, pc, Ti[2 * k]));
      Tr[2 * k + 1] = fmaf(q.z, pc, fmaf(-q.w, ps, Tr[2 * k + 1]));
      Ti[2 * k + 1] = fmaf(q.z, ps, fmaf( q.w, pc, Ti[2 * k + 1]));
    }
    const float tn = fmaf(pc, c1, -ps * s1);
    ps = fmaf(pc, s1, ps * c1);
    pc = tn;
  }
  float4* dst = (float4*)(tb + (long)bc * 8192 + y * 32 + wh * 16);
#pragma unroll
  for (int k = 0; k < 8; ++k)
    dst[k] = make_float4(Tr[2 * k], Ti[2 * k], Tr[2 * k + 1], Ti[2 * k + 1]);
}

// kE: 2048 blocks; block = 32 rows. Thread = (x=tid&127, rh=tid>>7): 16 rows.
// out(x)=C-S, out((256-x)&255)=C+S; col 128 via divergent tail (first 32 lanes).
// T staged [w][r] stride 34 float2, scale folded (1/256 for w=0, 2/256 else).
__global__ __launch_bounds__(256) void kE(const float2* __restrict__ tb,
                                          float* __restrict__ out) {
  __shared__ float2 tst[32 * 34];  // 8.5 KB
  const long row0 = (long)blockIdx.x * 32;
  const int tid = threadIdx.x;
  for (int i = tid; i < 1024; i += 256) {
    const int w = i & 31, r = i >> 5;
    const float2 v = tb[(row0 + r) * 32 + w];
    const float sc = w ? (2.0f / 256.0f) : (1.0f / 256.0f);
    tst[w * 34 + r] = make_float2(v.x * sc, v.y * sc);
  }
  __syncthreads();
  const int xx = tid & 127, rh = tid >> 7;
  float s1, c1;
  sincosf(TWO_PI * (float)xx / 256.0f, &s1, &c1);
  float C[16], S[16];
#pragma unroll
  for (int j = 0; j < 16; ++j) { C[j] = 0.f; S[j] = 0.f; }
  float pc = 1.f, ps = 0.f;
  const float* tbse = (const float*)tst + rh * 32;
  for (int w = 0; w < 32; ++w) {
    const float4* tf = (const float4*)(tbse + w * 68);
#pragma unroll
    for (int k = 0; k < 8; ++k) {
      const float4 q = tf[k];  // rows 2k,2k+1: (a,b,a,b)
      C[2 * k]     = fmaf(q.x, pc, C[2 * k]);
      S[2 * k]     = fmaf(q.y, ps, S[2 * k]);
      C[2 * k + 1] = fmaf(q.z, pc, C[2 * k + 1]);
      S[2 * k + 1] = fmaf(q.w, ps, S[2 * k + 1]);
    }
    const float tn = fmaf(pc, c1, -ps * s1);
    ps = fmaf(pc, s1, ps * c1);
    pc = tn;
  }
#pragma unroll
  for (int j = 0; j < 16; ++j) {
    const long row = row0 + rh * 16 + j;
    out[row * 256 + xx] = C[j] - S[j];
    out[row * 256 + ((256 - xx) & 255)] = C[j] + S[j];
  }
  if (tid < 32) {  // column x=128: sum (-1)^w a_w
    float ae = 0.f, ao = 0.f;
#pragma unroll
    for (int k = 0; k < 16; ++k) {
      ae += tst[(2 * k) * 34 + tid].x;
      ao += tst[(2 * k + 1) * 34 + tid].x;
    }
    out[(row0 + tid) * 256 + 128] = ae - ao;
  }
}

extern "C" void kernel_launch(void* const* d_in, const int* in_sizes, int n_in,
                              void* d_out, int out_size, void* d_ws, size_t ws_size,
                              hipStream_t stream) {
  const float* x = (const float*)d_in[0];
  const float* kin = (const float*)d_in[1];
  const float* rp = (const float*)d_in[2];
  float* out = (float*)d_out;
  char* ws = (char*)d_ws;

  float2* z1  = (float2*)(ws);                   // 0..16M
  float2* z2a = (float2*)(ws + (16ull << 20));   // 16..24M (z2b = z2a+524288)
  float2* kp  = (float2*)(ws + (24ull << 20));   // 24..24.5M
  float2* g   = (float2*)(ws);                   // 0..4M (over dead z1)
  float2* tb  = (float2*)(ws + (4ull << 20));    // 4..20M (over dead z1/z2a)

  kP<<<256, 256, 0, stream>>>(kin, rp, kp);
  kA<<<2048, 256, 0, stream>>>(x, z1);
  kB<<<512, 256, 0, stream>>>(z1, z2a);
  kC<<<1024, 256, 0, stream>>>(z2a, z2a + 524288, kp, g);
  kD<<<512, 256, 0, stream>>>(g, tb);
  kE<<<2048, 256, 0, stream>>>(tb, out);
}